// Round 18
// baseline (327.359 us; speedup 1.0000x reference)
//
#include <hip/hip_runtime.h>
#include <hip/hip_bf16.h>

#define HDIM 128
#define H3   384
#define RDIM 20
#define NPB  16   // nodes per block (node MLP)
#define EPB  64   // edges per block (edge stream kernel)
#define GRP  8    // edges per k-sweep group

typedef unsigned short u16;
typedef unsigned int   u32;

__device__ __forceinline__ u16 f2bf(float f) {
    __hip_bfloat16 h = __float2bfloat16(f);   // RNE
    return *(u16*)&h;
}
__device__ __forceinline__ float bflo(u32 u) {
    union { u32 i; float f; } x; x.i = u << 16; return x.f;
}
__device__ __forceinline__ float bfhi(u32 u) {
    union { u32 i; float f; } x; x.i = u & 0xffff0000u; return x.f;
}
__device__ __forceinline__ u32 pk(float lo, float hi) {
    return (u32)f2bf(lo) | ((u32)f2bf(hi) << 16);
}

// -------- Kernel 1: per-node MLP -> packed bf16, INTERLEAVED P3[node][ch][3] --------
// Layout: P3[node*384 + ch*3 + {0,1,2}] = (pss,psv),(pvv,vx),(vy,vz) — 12 B/channel
// contiguous, so the edge kernel gathers one dwordx3 per edge instead of 3 strided words.
__global__ __launch_bounds__(128) void node_mlp_kernel(
    const float* __restrict__ s, const float* __restrict__ W1,
    const float* __restrict__ b1, const float* __restrict__ W2,
    const float* __restrict__ b2, const float* __restrict__ v,
    u32* __restrict__ P3, int N)
{
    __shared__ float sS[NPB][HDIM];
    __shared__ float sH[NPB][HDIM];
    const int t  = threadIdx.x;
    const int n0 = blockIdx.x * NPB;

    #pragma unroll
    for (int n = 0; n < NPB; ++n) {
        int node = n0 + n;
        sS[n][t] = (node < N) ? s[(size_t)node * HDIM + t] : 0.f;
    }
    __syncthreads();

    float acc[NPB];
    #pragma unroll
    for (int n = 0; n < NPB; ++n) acc[n] = 0.f;
    for (int k = 0; k < HDIM; ++k) {
        float w = W1[k * HDIM + t];
        #pragma unroll
        for (int n = 0; n < NPB; ++n) acc[n] += sS[n][k] * w;
    }
    float bb = b1[t];
    #pragma unroll
    for (int n = 0; n < NPB; ++n) {
        float z = acc[n] + bb;
        sH[n][t] = z / (1.f + __expf(-z));   // silu
    }
    __syncthreads();

    float a0[NPB], a1[NPB], a2[NPB];
    #pragma unroll
    for (int n = 0; n < NPB; ++n) { a0[n] = 0.f; a1[n] = 0.f; a2[n] = 0.f; }
    for (int k2 = 0; k2 < HDIM / 2; ++k2) {
        float2 hv[NPB];
        #pragma unroll
        for (int n = 0; n < NPB; ++n) hv[n] = ((const float2*)sH[n])[k2];
        #pragma unroll
        for (int kk = 0; kk < 2; ++kk) {
            int k = 2 * k2 + kk;
            float w0 = W2[k * H3 + t];
            float w1 = W2[k * H3 + t + 128];
            float w2 = W2[k * H3 + t + 256];
            #pragma unroll
            for (int n = 0; n < NPB; ++n) {
                float h = kk ? hv[n].y : hv[n].x;
                a0[n] += h * w0;
                a1[n] += h * w1;
                a2[n] += h * w2;
            }
        }
    }
    float c0 = b2[t], c1 = b2[t + 128], c2 = b2[t + 256];
    #pragma unroll
    for (int n = 0; n < NPB; ++n) {
        int node = n0 + n;
        if (node < N) {
            size_t vb = (size_t)node * H3;
            float vx = v[vb + t], vy = v[vb + 128 + t], vz = v[vb + 256 + t];
            size_t pb = (size_t)node * H3 + 3 * t;      // interleaved: ch-major
            P3[pb]     = pk(a0[n] + c0, a1[n] + c1);    // (pss, psv)
            P3[pb + 1] = pk(a2[n] + c2, vx);            // (pvv, vx)
            P3[pb + 2] = pk(vy, vz);                    // (vy, vz)
        }
    }
}

// -------- CSR build (sort edges by destination) --------
__global__ void hist_kernel(const int* __restrict__ eidx, int* __restrict__ counts, int E)
{
    int e = blockIdx.x * 256 + threadIdx.x;
    if (e < E) atomicAdd(&counts[eidx[e]], 1);
}

__global__ __launch_bounds__(1024) void scan_kernel(
    const int* __restrict__ counts, int* __restrict__ rstart,
    int* __restrict__ cursor, int N)
{
    __shared__ int part[1024];
    const int t = threadIdx.x;
    const int C = 20;
    int loc[C];
    int s = 0;
    #pragma unroll
    for (int q = 0; q < C; ++q) {
        int idx = t * C + q;
        int c = (idx < N) ? counts[idx] : 0;
        loc[q] = s; s += c;
    }
    part[t] = s;
    __syncthreads();
    for (int off = 1; off < 1024; off <<= 1) {
        int vv = (t >= off) ? part[t - off] : 0;
        __syncthreads();
        part[t] += vv;
        __syncthreads();
    }
    int boff = (t > 0) ? part[t - 1] : 0;
    #pragma unroll
    for (int q = 0; q < C; ++q) {
        int idx = t * C + q;
        if (idx < N) {
            int st = boff + loc[q];
            rstart[idx] = st;
            cursor[idx] = st;
        }
    }
    if (t == 1023) rstart[N] = part[1023];
}

__global__ void scatter_kernel(const int* __restrict__ eidx, int* __restrict__ cursor,
                               int* __restrict__ eord, int E)
{
    int e = blockIdx.x * 256 + threadIdx.x;
    if (e < E) {
        int i = eidx[e];
        int pos = atomicAdd(&cursor[i], 1);
        eord[pos] = e;
    }
}

// -------- Kernel 2: edge streaming, k-sweep dot + single dwordx3 gather per edge --------
__global__ __launch_bounds__(128) void edge_stream_kernel(
    const int* __restrict__ eord, const int* __restrict__ eidx,
    const float* __restrict__ rbf, const float* __restrict__ cutoff,
    const float* __restrict__ evec, const float* __restrict__ Wr,
    const float* __restrict__ br, const u32* __restrict__ P3,
    float* __restrict__ ds, float* __restrict__ dv, int E)
{
    const int t    = threadIdx.x;
    const int base = blockIdx.x * EPB;
    const int cnt  = min(EPB, E - base);

    const float* wp = Wr + t;   // thread's cols: t, t+128, t+256; row stride H3
    const float br0 = br[t], br1 = br[t + 128], br2 = br[t + 256];

    __shared__ int   sI[EPB], sJ[EPB];
    __shared__ float sCut[EPB], sVx[EPB], sVy[EPB], sVz[EPB];
    __shared__ __attribute__((aligned(16))) float sRbf[EPB][RDIM];

    if (t < cnt) {
        int e   = eord[base + t];
        sI[t]   = eidx[e];
        sJ[t]   = eidx[E + e] * H3;
        sCut[t] = cutoff[e];
        sVx[t]  = evec[3 * e];
        sVy[t]  = evec[3 * e + 1];
        sVz[t]  = evec[3 * e + 2];
        const float4* rr = (const float4*)(rbf + (size_t)e * RDIM);
        float4* dst = (float4*)sRbf[t];
        #pragma unroll
        for (int j = 0; j < 5; ++j) dst[j] = rr[j];
    }
    __syncthreads();

    int   cur  = sI[0];
    float accs = 0.f, accx = 0.f, accy = 0.f, accz = 0.f;
    const int t3 = 3 * t;

    for (int g0 = 0; g0 < cnt; g0 += GRP) {
        // 1) one contiguous 12-B gather per edge (dwordx3) — 3x fewer mem instrs
        u32 pa[GRP], pb[GRP], pc[GRP];
        #pragma unroll
        for (int e = 0; e < GRP; ++e) {
            int q = g0 + e;
            const u32* p = P3 + sJ[(q < cnt) ? q : (cnt - 1)] + t3;
            pa[e] = p[0]; pb[e] = p[1]; pc[e] = p[2];   // adjacent -> dwordx3
        }

        // 2) k-sweep dot: 3 wr loads per k, 24 FMAs on broadcast rbf
        float d0[GRP], d1[GRP], d2[GRP];
        #pragma unroll
        for (int e = 0; e < GRP; ++e) { d0[e] = br0; d1[e] = br1; d2[e] = br2; }
        #pragma unroll 4
        for (int k = 0; k < RDIM; ++k) {
            float w0 = wp[k * H3];
            float w1 = wp[k * H3 + 128];
            float w2 = wp[k * H3 + 256];
            #pragma unroll
            for (int e = 0; e < GRP; ++e) {
                float r = sRbf[g0 + e][k];   // wave-uniform broadcast
                d0[e] += r * w0;
                d1[e] += r * w1;
                d2[e] += r * w2;
            }
        }

        // 3) epilogue per edge (run-boundary flush is block-uniform)
        #pragma unroll
        for (int e = 0; e < GRP; ++e) {
            int q = g0 + e;
            if (q < cnt) {
                if (sI[q] != cur) {
                    atomicAdd(&ds[(size_t)cur * HDIM + t], accs);
                    size_t dvi = (size_t)cur * H3;
                    atomicAdd(&dv[dvi + t],       accx);
                    atomicAdd(&dv[dvi + 128 + t], accy);
                    atomicAdd(&dv[dvi + 256 + t], accz);
                    accs = accx = accy = accz = 0.f;
                    cur = sI[q];
                }
                float cu = sCut[q];
                float ex = sVx[q], ey = sVy[q], ez = sVz[q];
                float pss = bflo(pa[e]), psv = bfhi(pa[e]);
                float pvv = bflo(pb[e]), vx  = bfhi(pb[e]);
                float vy  = bflo(pc[e]), vz  = bfhi(pc[e]);
                float xss = d0[e] * cu * pss;
                float xsv = d1[e] * cu * psv;
                float xvv = d2[e] * cu * pvv;
                float inner = vx * ex + vy * ey + vz * ez;
                float coef  = xsv + inner * xvv;
                accs += xss;
                accx += coef * ex;
                accy += coef * ey;
                accz += coef * ez;
            }
        }
    }
    atomicAdd(&ds[(size_t)cur * HDIM + t], accs);
    size_t dvi = (size_t)cur * H3;
    atomicAdd(&dv[dvi + t],       accx);
    atomicAdd(&dv[dvi + 128 + t], accy);
    atomicAdd(&dv[dvi + 256 + t], accz);
}

extern "C" void kernel_launch(void* const* d_in, const int* in_sizes, int n_in,
                              void* d_out, int out_size, void* d_ws, size_t ws_size,
                              hipStream_t stream)
{
    const float* s    = (const float*)d_in[0];
    const float* v    = (const float*)d_in[1];
    const float* rbf  = (const float*)d_in[2];
    const float* cut  = (const float*)d_in[3];
    const float* evec = (const float*)d_in[4];
    const float* W1   = (const float*)d_in[5];
    const float* b1   = (const float*)d_in[6];
    const float* W2   = (const float*)d_in[7];
    const float* b2   = (const float*)d_in[8];
    const float* Wr   = (const float*)d_in[9];
    const float* br   = (const float*)d_in[10];
    const int*   eidx = (const int*)d_in[11];

    const int N = in_sizes[0] / HDIM;   // 20000
    const int E = in_sizes[3];          // 400000

    float* out = (float*)d_out;
    float* ds  = out;                      // [N, H]
    float* dv  = out + (size_t)N * HDIM;   // [N, 3, H]

    // workspace layout (256B aligned chunks)
    char* w = (char*)d_ws;
    u32* P3 = (u32*)w;                     w += ((size_t)N * H3 * 4 + 255) / 256 * 256;
    int* counts = (int*)w;                 w += ((size_t)N * 4 + 255) / 256 * 256;
    int* rstart = (int*)w;                 w += ((size_t)(N + 1) * 4 + 255) / 256 * 256;
    int* cursor = (int*)w;                 w += ((size_t)N * 4 + 255) / 256 * 256;
    int* eord   = (int*)w;

    hipMemsetAsync(d_out, 0, (size_t)out_size * sizeof(float), stream);
    hipMemsetAsync(counts, 0, (size_t)N * sizeof(int), stream);

    node_mlp_kernel<<<(N + NPB - 1) / NPB, 128, 0, stream>>>(s, W1, b1, W2, b2, v, P3, N);
    hist_kernel<<<(E + 255) / 256, 256, 0, stream>>>(eidx, counts, E);
    scan_kernel<<<1, 1024, 0, stream>>>(counts, rstart, cursor, N);
    scatter_kernel<<<(E + 255) / 256, 256, 0, stream>>>(eidx, cursor, eord, E);
    edge_stream_kernel<<<(E + EPB - 1) / EPB, 128, 0, stream>>>(eord, eidx, rbf, cut,
                                                                evec, Wr, br, P3,
                                                                ds, dv, E);
}

// Round 19
// 321.661 us; speedup vs baseline: 1.0177x; 1.0177x over previous
//
#include <hip/hip_runtime.h>
#include <hip/hip_bf16.h>

#define HDIM 128
#define H3   384
#define RDIM 20
#define NPB  16   // nodes per block (node MLP)
#define EPB  64   // edges per block (edge stream kernel)
#define GRP  8    // edges per k-sweep group

typedef unsigned short u16;
typedef unsigned int   u32;

__device__ __forceinline__ u16 f2bf(float f) {
    __hip_bfloat16 h = __float2bfloat16(f);   // RNE
    return *(u16*)&h;
}
__device__ __forceinline__ float bflo(u32 u) {
    union { u32 i; float f; } x; x.i = u << 16; return x.f;
}
__device__ __forceinline__ float bfhi(u32 u) {
    union { u32 i; float f; } x; x.i = u & 0xffff0000u; return x.f;
}
__device__ __forceinline__ u32 pk(float lo, float hi) {
    return (u32)f2bf(lo) | ((u32)f2bf(hi) << 16);
}

// -------- Kernel 1: per-node MLP -> packed bf16 P3[node][3][128]; fuses v conv --------
__global__ __launch_bounds__(128) void node_mlp_kernel(
    const float* __restrict__ s, const float* __restrict__ W1,
    const float* __restrict__ b1, const float* __restrict__ W2,
    const float* __restrict__ b2, const float* __restrict__ v,
    u32* __restrict__ P3, int N)
{
    __shared__ float sS[NPB][HDIM];
    __shared__ float sH[NPB][HDIM];
    const int t  = threadIdx.x;
    const int n0 = blockIdx.x * NPB;

    #pragma unroll
    for (int n = 0; n < NPB; ++n) {
        int node = n0 + n;
        sS[n][t] = (node < N) ? s[(size_t)node * HDIM + t] : 0.f;
    }
    __syncthreads();

    float acc[NPB];
    #pragma unroll
    for (int n = 0; n < NPB; ++n) acc[n] = 0.f;
    for (int k = 0; k < HDIM; ++k) {
        float w = W1[k * HDIM + t];
        #pragma unroll
        for (int n = 0; n < NPB; ++n) acc[n] += sS[n][k] * w;
    }
    float bb = b1[t];
    #pragma unroll
    for (int n = 0; n < NPB; ++n) {
        float z = acc[n] + bb;
        sH[n][t] = z / (1.f + __expf(-z));   // silu
    }
    __syncthreads();

    float a0[NPB], a1[NPB], a2[NPB];
    #pragma unroll
    for (int n = 0; n < NPB; ++n) { a0[n] = 0.f; a1[n] = 0.f; a2[n] = 0.f; }
    for (int k2 = 0; k2 < HDIM / 2; ++k2) {
        float2 hv[NPB];
        #pragma unroll
        for (int n = 0; n < NPB; ++n) hv[n] = ((const float2*)sH[n])[k2];
        #pragma unroll
        for (int kk = 0; kk < 2; ++kk) {
            int k = 2 * k2 + kk;
            float w0 = W2[k * H3 + t];
            float w1 = W2[k * H3 + t + 128];
            float w2 = W2[k * H3 + t + 256];
            #pragma unroll
            for (int n = 0; n < NPB; ++n) {
                float h = kk ? hv[n].y : hv[n].x;
                a0[n] += h * w0;
                a1[n] += h * w1;
                a2[n] += h * w2;
            }
        }
    }
    float c0 = b2[t], c1 = b2[t + 128], c2 = b2[t + 256];
    #pragma unroll
    for (int n = 0; n < NPB; ++n) {
        int node = n0 + n;
        if (node < N) {
            size_t vb = (size_t)node * H3;
            float vx = v[vb + t], vy = v[vb + 128 + t], vz = v[vb + 256 + t];
            size_t pb = (size_t)node * H3 + t;
            P3[pb]       = pk(a0[n] + c0, a1[n] + c1);   // (pss, psv)
            P3[pb + 128] = pk(a2[n] + c2, vx);           // (pvv, vx)
            P3[pb + 256] = pk(vy, vz);                   // (vy, vz)
        }
    }
}

// -------- CSR build (sort edges by destination) --------
__global__ void hist_kernel(const int* __restrict__ eidx, int* __restrict__ counts, int E)
{
    int e = blockIdx.x * 256 + threadIdx.x;
    if (e < E) atomicAdd(&counts[eidx[e]], 1);
}

__global__ __launch_bounds__(1024) void scan_kernel(
    const int* __restrict__ counts, int* __restrict__ rstart,
    int* __restrict__ cursor, int N)
{
    __shared__ int part[1024];
    const int t = threadIdx.x;
    const int C = 20;
    int loc[C];
    int s = 0;
    #pragma unroll
    for (int q = 0; q < C; ++q) {
        int idx = t * C + q;
        int c = (idx < N) ? counts[idx] : 0;
        loc[q] = s; s += c;
    }
    part[t] = s;
    __syncthreads();
    for (int off = 1; off < 1024; off <<= 1) {
        int vv = (t >= off) ? part[t - off] : 0;
        __syncthreads();
        part[t] += vv;
        __syncthreads();
    }
    int boff = (t > 0) ? part[t - 1] : 0;
    #pragma unroll
    for (int q = 0; q < C; ++q) {
        int idx = t * C + q;
        if (idx < N) {
            int st = boff + loc[q];
            rstart[idx] = st;
            cursor[idx] = st;
        }
    }
    if (t == 1023) rstart[N] = part[1023];
}

__global__ void scatter_kernel(const int* __restrict__ eidx, int* __restrict__ cursor,
                               int* __restrict__ eord, int E)
{
    int e = blockIdx.x * 256 + threadIdx.x;
    if (e < E) {
        int i = eidx[e];
        int pos = atomicAdd(&cursor[i], 1);
        eord[pos] = e;
    }
}

// -------- Kernel 2: edge streaming with k-sweep dot (amortized Wr loads) --------
// Per 8-edge group: prefetch P3 gathers; k-loop loads wr(k) ONCE and applies it
// to all 8 edges via LDS-broadcast rbf reads. Wr traffic: 60/edge -> 7.5/edge.
__global__ __launch_bounds__(128) void edge_stream_kernel(
    const int* __restrict__ eord, const int* __restrict__ eidx,
    const float* __restrict__ rbf, const float* __restrict__ cutoff,
    const float* __restrict__ evec, const float* __restrict__ Wr,
    const float* __restrict__ br, const u32* __restrict__ P3,
    float* __restrict__ ds, float* __restrict__ dv, int E)
{
    const int t    = threadIdx.x;
    const int base = blockIdx.x * EPB;
    const int cnt  = min(EPB, E - base);

    const float* wp = Wr + t;   // thread's cols: t, t+128, t+256; row stride H3
    const float br0 = br[t], br1 = br[t + 128], br2 = br[t + 256];

    __shared__ int   sI[EPB], sJ[EPB];
    __shared__ float sCut[EPB], sVx[EPB], sVy[EPB], sVz[EPB];
    __shared__ __attribute__((aligned(16))) float sRbf[EPB][RDIM];

    if (t < cnt) {
        int e   = eord[base + t];
        sI[t]   = eidx[e];
        sJ[t]   = eidx[E + e] * H3;
        sCut[t] = cutoff[e];
        sVx[t]  = evec[3 * e];
        sVy[t]  = evec[3 * e + 1];
        sVz[t]  = evec[3 * e + 2];
        const float4* rr = (const float4*)(rbf + (size_t)e * RDIM);
        float4* dst = (float4*)sRbf[t];
        #pragma unroll
        for (int j = 0; j < 5; ++j) dst[j] = rr[j];
    }
    __syncthreads();

    int   cur  = sI[0];
    float accs = 0.f, accx = 0.f, accy = 0.f, accz = 0.f;

    for (int g0 = 0; g0 < cnt; g0 += GRP) {
        // 1) issue P3 gathers for the group (complete under the k-loop FMAs)
        u32 pa[GRP], pb[GRP], pc[GRP];
        #pragma unroll
        for (int e = 0; e < GRP; ++e) {
            int q = g0 + e;
            int idx = sJ[(q < cnt) ? q : (cnt - 1)] + t;
            pa[e] = P3[idx]; pb[e] = P3[idx + 128]; pc[e] = P3[idx + 256];
        }

        // 2) k-sweep dot: 3 wr loads per k, 24 FMAs on broadcast rbf
        float d0[GRP], d1[GRP], d2[GRP];
        #pragma unroll
        for (int e = 0; e < GRP; ++e) { d0[e] = br0; d1[e] = br1; d2[e] = br2; }
        #pragma unroll 4
        for (int k = 0; k < RDIM; ++k) {
            float w0 = wp[k * H3];
            float w1 = wp[k * H3 + 128];
            float w2 = wp[k * H3 + 256];
            #pragma unroll
            for (int e = 0; e < GRP; ++e) {
                float r = sRbf[g0 + e][k];   // wave-uniform broadcast
                d0[e] += r * w0;
                d1[e] += r * w1;
                d2[e] += r * w2;
            }
        }

        // 3) epilogue per edge (run-boundary flush is block-uniform)
        #pragma unroll
        for (int e = 0; e < GRP; ++e) {
            int q = g0 + e;
            if (q < cnt) {
                if (sI[q] != cur) {
                    atomicAdd(&ds[(size_t)cur * HDIM + t], accs);
                    size_t dvi = (size_t)cur * H3;
                    atomicAdd(&dv[dvi + t],       accx);
                    atomicAdd(&dv[dvi + 128 + t], accy);
                    atomicAdd(&dv[dvi + 256 + t], accz);
                    accs = accx = accy = accz = 0.f;
                    cur = sI[q];
                }
                float cu = sCut[q];
                float ex = sVx[q], ey = sVy[q], ez = sVz[q];
                float pss = bflo(pa[e]), psv = bfhi(pa[e]);
                float pvv = bflo(pb[e]), vx  = bfhi(pb[e]);
                float vy  = bflo(pc[e]), vz  = bfhi(pc[e]);
                float xss = d0[e] * cu * pss;
                float xsv = d1[e] * cu * psv;
                float xvv = d2[e] * cu * pvv;
                float inner = vx * ex + vy * ey + vz * ez;
                float coef  = xsv + inner * xvv;
                accs += xss;
                accx += coef * ex;
                accy += coef * ey;
                accz += coef * ez;
            }
        }
    }
    atomicAdd(&ds[(size_t)cur * HDIM + t], accs);
    size_t dvi = (size_t)cur * H3;
    atomicAdd(&dv[dvi + t],       accx);
    atomicAdd(&dv[dvi + 128 + t], accy);
    atomicAdd(&dv[dvi + 256 + t], accz);
}

extern "C" void kernel_launch(void* const* d_in, const int* in_sizes, int n_in,
                              void* d_out, int out_size, void* d_ws, size_t ws_size,
                              hipStream_t stream)
{
    const float* s    = (const float*)d_in[0];
    const float* v    = (const float*)d_in[1];
    const float* rbf  = (const float*)d_in[2];
    const float* cut  = (const float*)d_in[3];
    const float* evec = (const float*)d_in[4];
    const float* W1   = (const float*)d_in[5];
    const float* b1   = (const float*)d_in[6];
    const float* W2   = (const float*)d_in[7];
    const float* b2   = (const float*)d_in[8];
    const float* Wr   = (const float*)d_in[9];
    const float* br   = (const float*)d_in[10];
    const int*   eidx = (const int*)d_in[11];

    const int N = in_sizes[0] / HDIM;   // 20000
    const int E = in_sizes[3];          // 400000

    float* out = (float*)d_out;
    float* ds  = out;                      // [N, H]
    float* dv  = out + (size_t)N * HDIM;   // [N, 3, H]

    // workspace layout (256B aligned chunks)
    char* w = (char*)d_ws;
    u32* P3 = (u32*)w;                     w += ((size_t)N * H3 * 4 + 255) / 256 * 256;
    int* counts = (int*)w;                 w += ((size_t)N * 4 + 255) / 256 * 256;
    int* rstart = (int*)w;                 w += ((size_t)(N + 1) * 4 + 255) / 256 * 256;
    int* cursor = (int*)w;                 w += ((size_t)N * 4 + 255) / 256 * 256;
    int* eord   = (int*)w;

    hipMemsetAsync(d_out, 0, (size_t)out_size * sizeof(float), stream);
    hipMemsetAsync(counts, 0, (size_t)N * sizeof(int), stream);

    node_mlp_kernel<<<(N + NPB - 1) / NPB, 128, 0, stream>>>(s, W1, b1, W2, b2, v, P3, N);
    hist_kernel<<<(E + 255) / 256, 256, 0, stream>>>(eidx, counts, E);
    scan_kernel<<<1, 1024, 0, stream>>>(counts, rstart, cursor, N);
    scatter_kernel<<<(E + 255) / 256, 256, 0, stream>>>(eidx, cursor, eord, E);
    edge_stream_kernel<<<(E + EPB - 1) / EPB, 128, 0, stream>>>(eord, eidx, rbf, cut,
                                                                evec, Wr, br, P3,
                                                                ds, dv, E);
}